// Round 1
// baseline (111.813 us; speedup 1.0000x reference)
//
#include <hip/hip_runtime.h>
#include <math.h>

#define Bn  16
#define Hn  384
#define Wn  512
#define HWn (Hn * Wn)

__global__ __launch_bounds__(256) void ProjectionLayer_678604833211_kernel(
    const float* __restrict__ src,    // [B,H,W,3]
    const float* __restrict__ depth,  // [B,H,W]
    const float* __restrict__ pose,   // [B,6]
    const float* __restrict__ intr,   // [3,3]
    float* __restrict__ out)          // [B,H,W,3]
{
    // S[0..11]  = proj rows 0..2 (4 cols each)  (proj = K4 @ T, top 3 rows)
    // S[12..15] = inv_fx, -cx/fx, inv_fy, -cy/fy
    __shared__ float S[16];
    const int b = blockIdx.y;

    if (threadIdx.x == 0) {
        const float fx = intr[0], cx = intr[2], fy = intr[4], cy = intr[5];
        const float tx = pose[b * 6 + 0] * 0.01f;
        const float ty = pose[b * 6 + 1] * 0.01f;
        const float tz = pose[b * 6 + 2] * 0.01f;
        const float rx = pose[b * 6 + 3] * 0.001f;
        const float ry = pose[b * 6 + 4] * 0.001f;
        const float rz = pose[b * 6 + 5] * 0.001f;
        const float cX = cosf(rx), sX = sinf(rx);
        const float cY = cosf(ry), sY = sinf(ry);
        const float cZ = cosf(rz), sZ = sinf(rz);
        // R = (Rz @ Ry) @ Rx   (match reference associativity)
        const float R00 = cZ * cY;
        const float R01 = -sZ * cX + cZ * sY * sX;
        const float R02 =  sZ * sX + cZ * sY * cX;
        const float R10 = sZ * cY;
        const float R11 =  cZ * cX + sZ * sY * sX;
        const float R12 = -cZ * sX + sZ * sY * cX;
        const float R20 = -sY;
        const float R21 = cY * sX;
        const float R22 = cY * cX;
        // proj = K4 @ [R | t]
        S[0]  = fx * R00 + cx * R20;
        S[1]  = fx * R01 + cx * R21;
        S[2]  = fx * R02 + cx * R22;
        S[3]  = fx * tx  + cx * tz;
        S[4]  = fy * R10 + cy * R20;
        S[5]  = fy * R11 + cy * R21;
        S[6]  = fy * R12 + cy * R22;
        S[7]  = fy * ty  + cy * tz;
        S[8]  = R20;
        S[9]  = R21;
        S[10] = R22;
        S[11] = tz;
        S[12] = 1.0f / fx;
        S[13] = -cx / fx;
        S[14] = 1.0f / fy;
        S[15] = -cy / fy;
    }
    __syncthreads();

    const int tid = blockIdx.x * blockDim.x + threadIdx.x;
    if (tid >= HWn) return;
    const int u = tid & (Wn - 1);
    const int v = tid >> 9;  // Wn == 512

    const float d = depth[(size_t)b * HWn + tid];

    // cam = depth * K^-1 @ [u, v, 1]
    const float camx = fmaf((float)u, S[12], S[13]) * d;
    const float camy = fmaf((float)v, S[14], S[15]) * d;
    // camz = d

    const float p0 = fmaf(S[0], camx, fmaf(S[1], camy, fmaf(S[2],  d, S[3])));
    const float p1 = fmaf(S[4], camx, fmaf(S[5], camy, fmaf(S[6],  d, S[7])));
    const float p2 = fmaf(S[8], camx, fmaf(S[9], camy, fmaf(S[10], d, S[11])));

    const float inv = 1.0f / (p2 + 1e-10f);
    const float x = p0 * inv;
    const float y = p1 * inv;

    const float x0f = floorf(x), y0f = floorf(y);
    const float ax = x - x0f;           // (x - x0f)
    const float ay = y - y0f;
    const float bx = (x0f + 1.0f) - x;  // (x1f - x), match reference rounding
    const float by = (y0f + 1.0f) - y;
    const float wa = bx * by;
    const float wb = bx * ay;
    const float wc = ax * by;
    const float wd = ax * ay;

    const int x0 = (int)fminf(fmaxf(x0f,        0.0f), (float)(Wn - 1));
    const int x1 = (int)fminf(fmaxf(x0f + 1.0f, 0.0f), (float)(Wn - 1));
    const int y0 = (int)fminf(fmaxf(y0f,        0.0f), (float)(Hn - 1));
    const int y1 = (int)fminf(fmaxf(y0f + 1.0f, 0.0f), (float)(Hn - 1));

    const float* base = src + (size_t)b * HWn * 3;
    const float* pa = base + (size_t)(y0 * Wn + x0) * 3;
    const float* pb = base + (size_t)(y1 * Wn + x0) * 3;
    const float* pc = base + (size_t)(y0 * Wn + x1) * 3;
    const float* pd = base + (size_t)(y1 * Wn + x1) * 3;

    const float o0 = wa * pa[0] + wb * pb[0] + wc * pc[0] + wd * pd[0];
    const float o1 = wa * pa[1] + wb * pb[1] + wc * pc[1] + wd * pd[1];
    const float o2 = wa * pa[2] + wb * pb[2] + wc * pc[2] + wd * pd[2];

    float* q = out + ((size_t)b * HWn + tid) * 3;
    q[0] = o0;
    q[1] = o1;
    q[2] = o2;
}

extern "C" void kernel_launch(void* const* d_in, const int* in_sizes, int n_in,
                              void* d_out, int out_size, void* d_ws, size_t ws_size,
                              hipStream_t stream) {
    const float* src   = (const float*)d_in[0];  // [16,384,512,3]
    const float* depth = (const float*)d_in[1];  // [16,384,512]
    const float* pose  = (const float*)d_in[2];  // [16,6]
    const float* intr  = (const float*)d_in[3];  // [3,3]
    float* out = (float*)d_out;

    dim3 grid(HWn / 256, Bn);
    dim3 block(256);
    ProjectionLayer_678604833211_kernel<<<grid, block, 0, stream>>>(
        src, depth, pose, intr, out);
}